// Round 5
// baseline (359.265 us; speedup 1.0000x reference)
//
#include <hip/hip_runtime.h>
#include <hip/hip_bf16.h>

#define N_NODES 100000
#define N_EDGES 3200000
#define IN_C 128
#define HID_C 64
#define OUT_C 64

#define NBUCKET 196          // ceil(N_NODES / 512); bucket = target >> 9
#define SC_EDGES 4096        // edges per scatter block
#define SC_GRID 782          // ceil(E / SC_EDGES)
#define CAP 18432            // padded bucket capacity (mean 16384 + 16 sigma)

struct EdgeRec { int s; float v; };   // source node, raw edge weight w

typedef float f32x2 __attribute__((ext_vector_type(2)));
typedef float f32x4 __attribute__((ext_vector_type(4)));
typedef short bf16x8 __attribute__((ext_vector_type(8)));
union F8 { uint4 u; bf16x8 f; };

// staged record: 8 B. x = f32 bits of w; y = s (17 bits) | t_local<<17 (9 bits)
__device__ __forceinline__ unsigned pack_bf16(float lo, float hi) {
    unsigned short l = __hip_bfloat16_raw(__float2bfloat16(lo)).x;
    unsigned short h = __hip_bfloat16_raw(__float2bfloat16(hi)).x;
    return ((unsigned)h << 16) | l;
}
__device__ __forceinline__ float bf_lo(unsigned u) {
    union { unsigned u; float f; } c; c.u = u << 16; return c.f;
}
__device__ __forceinline__ float bf_hi(unsigned u) {
    union { unsigned u; float f; } c; c.u = u & 0xffff0000u; return c.f;
}
// unpack a bf16 pair into an f32x2 register pair (lshl + and, exact)
__device__ __forceinline__ f32x2 bfp(unsigned u) {
    union { unsigned u; float f; } lo, hi;
    lo.u = u << 16; hi.u = u & 0xffff0000u;
    f32x2 r; r.x = lo.f; r.y = hi.f; return r;
}
// packed f32 FMA: acc = a*w + acc  (v_pk_fma_f32, full-rate on gfx950)
__device__ __forceinline__ void pk_fma(f32x2& acc, f32x2 a, f32x2 w) {
    asm("v_pk_fma_f32 %0, %1, %2, %0" : "+v"(acc) : "v"(a), "v"(w));
}
// accumulate one edge's 8 channels (one uint4) with weight w
__device__ __forceinline__ void edge_acc(f32x2* acc2, uint4 u, float w) {
    f32x2 wv; wv.x = w; wv.y = w;
    pk_fma(acc2[0], bfp(u.x), wv);
    pk_fma(acc2[1], bfp(u.y), wv);
    pk_fma(acc2[2], bfp(u.z), wv);
    pk_fma(acc2[3], bfp(u.w), wv);
}
// v_cvt_pk_bf16_f32: two f32 -> packed bf16 pair (lo in low half), RNE
__device__ __forceinline__ unsigned cvt_pk_bf16(float lo, float hi) {
    unsigned r;
    asm("v_cvt_pk_bf16_f32 %0, %1, %2" : "=v"(r) : "v"(lo), "v"(hi));
    return r;
}
// split 8 f32 into bf16 hi-frag + bf16 lo-frag (residual), packed as uint4
__device__ __forceinline__ void split_frag(const float* f, uint4& hi4, uint4& lo4) {
    unsigned hi[4], lo[4];
    #pragma unroll
    for (int p = 0; p < 4; ++p) {
        hi[p] = cvt_pk_bf16(f[2 * p], f[2 * p + 1]);
        float r0 = f[2 * p]     - bf_lo(hi[p]);
        float r1 = f[2 * p + 1] - bf_hi(hi[p]);
        lo[p] = cvt_pk_bf16(r0, r1);
    }
    hi4 = make_uint4(hi[0], hi[1], hi[2], hi[3]);
    lo4 = make_uint4(lo[0], lo[1], lo[2], lo[3]);
}

// ---- coarse scatter: edges -> padded bucket-major staging ----------------
__global__ __launch_bounds__(256) void scatter_coarse(const int* __restrict__ ei,
                                                      const float* __restrict__ ew,
                                                      int* __restrict__ gcursor,
                                                      uint2* __restrict__ tmp) {
    __shared__ int hist[256];
    __shared__ int scan[256];
    __shared__ int lcur[256];
    __shared__ int adj[256];
    __shared__ uint2 rec[SC_EDGES];           // 32 KB
    __shared__ unsigned char bk[SC_EDGES];    // 4 KB
    int tid = threadIdx.x;
    hist[tid] = 0;
    __syncthreads();
    int base = blockIdx.x * SC_EDGES;
    unsigned ys[16];
    float    ws[16];
    int      bs[16];
    for (int i = 0; i < 16; ++i) {
        int e = base + i * 256 + tid;
        if (e < N_EDGES) {
            int t = ei[N_EDGES + e];
            bs[i] = t >> 9;
            ys[i] = (unsigned)ei[e] | ((unsigned)(t & 511) << 17);
            ws[i] = ew[e];
            atomicAdd(&hist[bs[i]], 1);
        } else bs[i] = -1;
    }
    __syncthreads();
    // exclusive scan of hist
    int v = hist[tid];
    scan[tid] = v;
    __syncthreads();
    for (int off = 1; off < 256; off <<= 1) {
        int t = scan[tid];
        int add = (tid >= off) ? scan[tid - off] : 0;
        __syncthreads();
        scan[tid] = t + add;
        __syncthreads();
    }
    int excl = scan[tid] - v;
    int gb = (v > 0) ? atomicAdd(&gcursor[tid], v) : 0;
    lcur[tid] = excl;
    adj[tid] = tid * CAP + gb - excl;  // global slot for LDS slot j: adj[b]+j
    __syncthreads();
    // place edges into LDS bucket-major
    for (int i = 0; i < 16; ++i) {
        if (bs[i] >= 0) {
            int j = atomicAdd(&lcur[bs[i]], 1);
            rec[j] = make_uint2(__float_as_uint(ws[i]), ys[i]);
            bk[j] = (unsigned char)bs[i];
        }
    }
    __syncthreads();
    // run-coalesced write-out
    int count = N_EDGES - base;
    if (count > SC_EDGES) count = SC_EDGES;
    for (int j = tid; j < count; j += 256) {
        int b = bk[j];
        tmp[adj[b] + j] = rec[j];
    }
}

// ---- exclusive scan of bucket counts -> dense ed bases -------------------
__global__ __launch_bounds__(256) void bucket_scan(const int* __restrict__ gcnt,
                                                   int* __restrict__ start) {
    __shared__ int s[256];
    int tid = threadIdx.x;
    int v = gcnt[tid];
    s[tid] = v;
    __syncthreads();
    for (int off = 1; off < 256; off <<= 1) {
        int t = s[tid];
        int add = (tid >= off) ? s[tid - off] : 0;
        __syncthreads();
        s[tid] = t + add;
        __syncthreads();
    }
    start[tid] = s[tid] - v;
    if (tid == 255) start[256] = s[255];   // == N_EDGES
}

// ---- per-bucket counting sort + rowptr + dis (one block per bucket) ------
__global__ __launch_bounds__(512) void fine_sort(const int* __restrict__ start,
                                                 const uint2* __restrict__ tmpPad,
                                                 int* __restrict__ rowptr,
                                                 float* __restrict__ dis,
                                                 EdgeRec* __restrict__ ed) {
    __shared__ int   cnt[512];
    __shared__ float wdeg[512];
    __shared__ int   s[512];
    int tid = threadIdx.x;
    int nodeBase = blockIdx.x << 9;
    int bb = start[blockIdx.x];
    int nEdge = start[blockIdx.x + 1] - bb;
    const uint2* tb = tmpPad + (size_t)blockIdx.x * CAP;
    cnt[tid] = 0;
    wdeg[tid] = 0.f;
    __syncthreads();
    for (int e = tid; e < nEdge; e += 512) {
        uint2 r = tb[e];
        int l = (r.y >> 17) & 511;
        atomicAdd(&cnt[l], 1);
        atomicAdd(&wdeg[l], __uint_as_float(r.x));
    }
    __syncthreads();
    int v = cnt[tid];
    s[tid] = v;
    __syncthreads();
    for (int off = 1; off < 512; off <<= 1) {
        int t = s[tid];
        int add = (tid >= off) ? s[tid - off] : 0;
        __syncthreads();
        s[tid] = t + add;
        __syncthreads();
    }
    int excl = s[tid] - v;
    int node = nodeBase + tid;
    if (node < N_NODES) {
        rowptr[node] = bb + excl;
        dis[node] = rsqrtf(wdeg[tid] + 1.0f);   // +1 = self-loop weight
    }
    if (node == N_NODES) rowptr[N_NODES] = N_EDGES;
    cnt[tid] = excl;       // reuse as cursor
    __syncthreads();
    for (int e = tid; e < nEdge; e += 512) {
        uint2 r = tb[e];
        int l = (r.y >> 17) & 511;
        int p = atomicAdd(&cnt[l], 1);
        EdgeRec o;
        o.s = (int)(r.y & 0x1FFFFu);
        o.v = __uint_as_float(r.x);
        ed[bb + p] = o;
    }
}

// ---- MFMA matmul: h = bf16( dis[row] * (X @ W) ), K = 128 or 64 ----------
// 3-pass bf16 hi/lo split (Markidis): X = Xh + Xl, W = Wh + Wl;
// acc += Xh@Wh + Xh@Wl + Xl@Wh in fp32 MFMA accumulators. Residual error
// ~2^-17 relative -- far below the bf16 output quantization (2^-9) that
// already dominates absmax, so h is numerically identical to the fp32 path.
// Round-4 restructure: R3's grid-stride (1250 blocks x 5 tiles) serialized
// load->split->MFMA->epilogue chains per wave (depth-2 MLP) => ~50 us,
// latency-bound. Now ONE 16-row tile per block (grid = 6250) and ALL A-tile
// loads issued up front (8 dwordx4 in flight for K=128); cross-tile overlap
// comes from block-level TLP instead of a serial in-wave loop.
// 4 waves/block; wave w owns a 16-col block; B-fragments (hi+lo) built from
// global W and held in registers. No LDS. Per-tile FP order identical to R3.
template<int K>
__global__ __launch_bounds__(256) void mm_mfma(const float* __restrict__ X,
                                               const float* __restrict__ W,
                                               const float* __restrict__ dis,
                                               unsigned* __restrict__ h) {
    constexpr int NKS = K / 32;
    int wv = threadIdx.x >> 6;        // wave id = col-block 0..3
    int l  = threadIdx.x & 63;
    int lr = l & 15;                  // A-row / B-col within tile
    int kr = l >> 4;                  // k sub-block: k = ks*32 + kr*8 + j
    int col = wv * 16 + lr;
    int row0 = blockIdx.x * 16;
    // ---- issue all A loads up front (8 B-deep load queue for K=128) ----
    const float* xbase = X + (size_t)(row0 + lr) * K + kr * 8;
    float4 xa[NKS], xb[NKS];
    #pragma unroll
    for (int ks = 0; ks < NKS; ++ks) {
        const float4* xp = (const float4*)(xbase + ks * 32);
        xa[ks] = xp[0];
        xb[ks] = xp[1];
    }
    // ---- B fragments (hi/lo), from global W (L2-resident, 32/16 KB) ----
    F8 bhi[NKS], blo[NKS];
    #pragma unroll
    for (int ks = 0; ks < NKS; ++ks) {
        const float* wp = W + (ks * 32 + kr * 8) * 64 + col;
        float f[8];
        #pragma unroll
        for (int j = 0; j < 8; ++j) f[j] = wp[j * 64];
        split_frag(f, bhi[ks].u, blo[ks].u);
    }
    f32x4 acc = {0.f, 0.f, 0.f, 0.f};
    #pragma unroll
    for (int ks = 0; ks < NKS; ++ks) {
        float f[8] = {xa[ks].x, xa[ks].y, xa[ks].z, xa[ks].w,
                      xb[ks].x, xb[ks].y, xb[ks].z, xb[ks].w};
        F8 ahi, alo;
        split_frag(f, ahi.u, alo.u);
        acc = __builtin_amdgcn_mfma_f32_16x16x32_bf16(ahi.f, bhi[ks].f, acc, 0, 0, 0);
        acc = __builtin_amdgcn_mfma_f32_16x16x32_bf16(ahi.f, blo[ks].f, acc, 0, 0, 0);
        acc = __builtin_amdgcn_mfma_f32_16x16x32_bf16(alo.f, bhi[ks].f, acc, 0, 0, 0);
    }
    int rbase = row0 + kr * 4;
    float v0 = acc[0] * dis[rbase + 0];
    float v1 = acc[1] * dis[rbase + 1];
    float v2 = acc[2] * dis[rbase + 2];
    float v3 = acc[3] * dis[rbase + 3];
    float o0 = __shfl_xor(v0, 1, 64);
    float o1 = __shfl_xor(v1, 1, 64);
    float o2 = __shfl_xor(v2, 1, 64);
    float o3 = __shfl_xor(v3, 1, 64);
    if ((lr & 1) == 0) {
        int ci = col >> 1;
        h[(rbase + 0) * 32 + ci] = pack_bf16(v0, o0);
        h[(rbase + 1) * 32 + ci] = pack_bf16(v1, o1);
        h[(rbase + 2) * 32 + ci] = pack_bf16(v2, o2);
        h[(rbase + 3) * 32 + ci] = pack_bf16(v3, o3);
    }
}

// ---- CSR aggregate + fused epilogue (bf16 dis-scaled h rows, 128 B) ------
// one wave per node; 8 groups of 8 lanes; rows mask-padded to whole
// 32-edge batches (clamped index + zero weight); <=64 VGPR pinned.
__global__ __launch_bounds__(256, 8) void agg_kernel(const int* __restrict__ rowptr,
                                                     const EdgeRec* __restrict__ ed,
                                                     const unsigned* __restrict__ h,
                                                     const float* __restrict__ dis,
                                                     const float* __restrict__ b,
                                                     float* __restrict__ out,
                                                     int relu) {
    int node = blockIdx.x * 4 + (threadIdx.x >> 6);
    int lane = threadIdx.x & 63;
    int g = lane >> 3;        // edge group 0..7
    int cl = lane & 7;        // channel octet: channels 8*cl .. 8*cl+7
    int beg = rowptr[node];
    int end = rowptr[node + 1];
    const uint4* h16 = (const uint4*)h;                   // 8 uint4 per row
    const char*  hb  = (const char*)h + (size_t)cl * 16;  // lane's slice base
    float d  = dis[node];
    uint4 us = h16[(size_t)node * 8 + cl];
    f32x2 acc2[4];
    acc2[0] = 0.f; acc2[1] = 0.f; acc2[2] = 0.f; acc2[3] = 0.f;
    int n = end - beg;            // in-degree (excl self)
    int nb = (n + 31) >> 5;       // 32-edge batches, wave-uniform
    int nm1 = n - 1;
    uint2 q0, q1, q2, q3;
    if (nb > 0) {
        q0 = *(const uint2*)(ed + beg + min(g,      nm1));
        q1 = *(const uint2*)(ed + beg + min(g + 8,  nm1));
        q2 = *(const uint2*)(ed + beg + min(g + 16, nm1));
        q3 = *(const uint2*)(ed + beg + min(g + 24, nm1));
        for (int bt = 0; bt < nb; ++bt) {
            int ob = (bt << 5) + g;
            float w0 = (ob      < n) ? __uint_as_float(q0.y) : 0.f;
            float w1 = (ob + 8  < n) ? __uint_as_float(q1.y) : 0.f;
            float w2 = (ob + 16 < n) ? __uint_as_float(q2.y) : 0.f;
            float w3 = (ob + 24 < n) ? __uint_as_float(q3.y) : 0.f;
            uint4 u0 = *(const uint4*)(hb + ((size_t)(unsigned)q0.x << 7));
            uint4 u1 = *(const uint4*)(hb + ((size_t)(unsigned)q1.x << 7));
            uint4 u2 = *(const uint4*)(hb + ((size_t)(unsigned)q2.x << 7));
            uint4 u3 = *(const uint4*)(hb + ((size_t)(unsigned)q3.x << 7));
            if (bt + 1 < nb) {
                int on = ob + 32;
                q0 = *(const uint2*)(ed + beg + min(on,      nm1));
                q1 = *(const uint2*)(ed + beg + min(on + 8,  nm1));
                q2 = *(const uint2*)(ed + beg + min(on + 16, nm1));
                q3 = *(const uint2*)(ed + beg + min(on + 24, nm1));
            }
            edge_acc(acc2, u0, w0);
            edge_acc(acc2, u1, w1);
            edge_acc(acc2, u2, w2);
            edge_acc(acc2, u3, w3);
        }
    }
    float acc[8] = { acc2[0].x, acc2[0].y, acc2[1].x, acc2[1].y,
                     acc2[2].x, acc2[2].y, acc2[3].x, acc2[3].y };
    #pragma unroll
    for (int kk = 0; kk < 8; ++kk) {
        acc[kk] += __shfl_xor(acc[kk], 8, 64);
        acc[kk] += __shfl_xor(acc[kk], 16, 64);
        acc[kk] += __shfl_xor(acc[kk], 32, 64);
    }
    if (g == 0) {
        float hs[8] = { bf_lo(us.x), bf_hi(us.x), bf_lo(us.y), bf_hi(us.y),
                        bf_lo(us.z), bf_hi(us.z), bf_lo(us.w), bf_hi(us.w) };
        const float4* b4 = (const float4*)b;
        float4 bv0 = b4[cl * 2], bv1 = b4[cl * 2 + 1];
        float4 v0, v1;
        v0.x = d * (acc[0] + hs[0]) + bv0.x;
        v0.y = d * (acc[1] + hs[1]) + bv0.y;
        v0.z = d * (acc[2] + hs[2]) + bv0.z;
        v0.w = d * (acc[3] + hs[3]) + bv0.w;
        v1.x = d * (acc[4] + hs[4]) + bv1.x;
        v1.y = d * (acc[5] + hs[5]) + bv1.y;
        v1.z = d * (acc[6] + hs[6]) + bv1.z;
        v1.w = d * (acc[7] + hs[7]) + bv1.w;
        if (relu) {
            v0.x = fmaxf(v0.x, 0.f); v0.y = fmaxf(v0.y, 0.f);
            v0.z = fmaxf(v0.z, 0.f); v0.w = fmaxf(v0.w, 0.f);
            v1.x = fmaxf(v1.x, 0.f); v1.y = fmaxf(v1.y, 0.f);
            v1.z = fmaxf(v1.z, 0.f); v1.w = fmaxf(v1.w, 0.f);
        }
        float4* o4 = (float4*)out;
        o4[node * 16 + cl * 2]     = v0;
        o4[node * 16 + cl * 2 + 1] = v1;
    }
}

extern "C" void kernel_launch(void* const* d_in, const int* in_sizes, int n_in,
                              void* d_out, int out_size, void* d_ws, size_t ws_size,
                              hipStream_t stream) {
    const float* x  = (const float*)d_in[0];
    const int*   ei = (const int*)d_in[1];   // [2, E]: sources then targets
    const float* ew = (const float*)d_in[2];
    const float* W1 = (const float*)d_in[3];
    const float* b1 = (const float*)d_in[4];
    const float* W2 = (const float*)d_in[5];
    const float* b2 = (const float*)d_in[6];
    float* out = (float*)d_out;

    // workspace carve-up (256 B aligned). tmpPad (28.9 MB, padded buckets)
    // is dead after fine_sort; bf16 h (12.8 MB) + f32 a (25.6 MB) overlay it.
    char* p = (char*)d_ws;
    auto carve = [&](size_t bytes) { char* r = p; p += (bytes + 255) & ~(size_t)255; return r; };
    float*    dis     = (float*)carve(N_NODES * 4);
    int*      rowptr  = (int*)carve((N_NODES + 1) * 4);
    int*      start   = (int*)carve(257 * 4);
    int*      gcursor = (int*)carve(256 * 4);
    EdgeRec*  ed      = (EdgeRec*)carve((size_t)N_EDGES * 8);
    size_t    r2sz    = (size_t)NBUCKET * CAP * 8;                 // 28.9 MB
    size_t    hasz    = (size_t)N_NODES * 64 * 6;                  // 38.4 MB
    char*     r2      = carve(r2sz > hasz ? r2sz : hasz);
    uint2*    tmpPad  = (uint2*)r2;
    unsigned* h       = (unsigned*)r2;                             // 12.8 MB
    float*    a       = (float*)(r2 + (size_t)N_NODES * 64 * 2);   // 25.6 MB

    // --- CSR build: direct padded reservation, no pre-histogram ---
    hipMemsetAsync(gcursor, 0, 256 * sizeof(int), stream);
    scatter_coarse<<<SC_GRID, 256, 0, stream>>>(ei, ew, gcursor, tmpPad);
    bucket_scan<<<1, 256, 0, stream>>>(gcursor, start);
    fine_sort<<<NBUCKET, 512, 0, stream>>>(start, tmpPad, rowptr, dis, ed);

    // --- layer 1: h = bf16(dis.(x@W1)) ; a = relu(agg(h) + b1) ---
    mm_mfma<IN_C><<<N_NODES / 16, 256, 0, stream>>>(x, W1, dis, h);
    agg_kernel<<<N_NODES / 4, 256, 0, stream>>>(rowptr, ed, h, dis, b1, a, 1);

    // --- layer 2: h = bf16(dis.(a@W2)) ; out = agg(h) + b2 ---
    mm_mfma<HID_C><<<N_NODES / 16, 256, 0, stream>>>(a, W2, dis, h);
    agg_kernel<<<N_NODES / 4, 256, 0, stream>>>(rowptr, ed, h, dis, b2, out, 0);
}